// Round 12
// baseline (48.508 us; speedup 1.0000x reference)
//
#include <hip/hip_runtime.h>
#include <stdint.h>

typedef __bf16 bf16x8 __attribute__((ext_vector_type(8)));
typedef float  f32x4  __attribute__((ext_vector_type(4)));

#define HW   3136
#define WID  56
#define CIN  128
#define SQ   32

// workspace layout (bytes unless noted)
#define OFF_BSQ 0              // f32[32]  (float offset 0)
#define OFF_BE  32             // f32[256] (float offset 32) e1 then e3
#define WSQF_BYTES_OFF 1152    // bf16 [2mf*4kc][64 lane][8] = 8192 B
#define WE1F_BYTES_OFF 9344    // bf16 [8 mf][64 lane][8] = 8192 B
#define WE3F_BYTES_OFF 17536   // bf16 [8 mf][9 tap][64 lane][8] = 73728 B

__device__ __forceinline__ float quant_w8(float x){
  float xc = fminf(fmaxf(x,-1.f),1.f);
  return fminf(rintf(xc*128.f)*0.0078125f, 0.9921875f);
}
// weight as integer n = 128*wq in [-128,127], stored as exact bf16
__device__ __forceinline__ ushort wq_int_bf16(float x){
  float xc = fminf(fmaxf(x,-1.f),1.f);
  float n = fminf(rintf(xc*128.f), 127.f);
  return (ushort)(__float_as_uint(n)>>16);
}
__device__ __forceinline__ uint pack2f(float a, float b){
  return (__float_as_uint(a)>>16) | (__float_as_uint(b)&0xffff0000u);
}

__global__ void prep_kernel(const float* __restrict__ wsq, const float* __restrict__ bsq,
                            const float* __restrict__ we1, const float* __restrict__ be1,
                            const float* __restrict__ we3, const float* __restrict__ be3,
                            float* __restrict__ ws){
  int tid = blockIdx.x*blockDim.x+threadIdx.x;
  int nth = gridDim.x*blockDim.x;
  ushort* wsqf = (ushort*)((char*)ws + WSQF_BYTES_OFF);
  ushort* we1f = (ushort*)((char*)ws + WE1F_BYTES_OFF);
  ushort* we3f = (ushort*)((char*)ws + WE3F_BYTES_OFF);
  for (int i=tid;i<SQ;i+=nth) ws[OFF_BSQ+i]=quant_w8(bsq[i]);
  for (int i=tid;i<256;i+=nth) ws[OFF_BE+i] = (i<128)? quant_w8(be1[i]) : quant_w8(be3[i-128]);
  // squeeze W frags: A[co=mf*16+(l&15)][ci=kc*32+(l>>4)*8+j], src wsq (32,128)
  for (int i=tid;i<4096;i+=nth){
    int mfkc=i>>9, l=(i>>3)&63, j=i&7;
    int mf=mfkc>>2, kc=mfkc&3;
    int co=mf*16+(l&15), ci=kc*32+(l>>4)*8+j;
    wsqf[i] = wq_int_bf16(wsq[co*CIN+ci]);
  }
  // e1 frags: [co=mf*16+(l&15)][k=ci=(l>>4)*8+j], src we1 (128,32)
  for (int i=tid;i<4096;i+=nth){
    int mf=i>>9, l=(i>>3)&63, j=i&7;
    int co=mf*16+(l&15), ci=(l>>4)*8+j;
    we1f[i] = wq_int_bf16(we1[co*SQ+ci]);
  }
  // e3 frags per tap, src we3 (128,32,3,3)
  for (int i=tid;i<36864;i+=nth){
    int mf=i/4608, r=i-mf*4608, t=r>>9, l=(r>>3)&63, j=r&7;
    int co=mf*16+(l&15), ci=(l>>4)*8+j;
    we3f[i] = wq_int_bf16(we3[(co*SQ+ci)*9+t]);
  }
}

// load 32 x-values for local halo block bl (16 px) into dst[32]; lp in [0,560)
#define LOADX(dst, bl) { \
  int g_ = gbase + (bl)*16 + colg; \
  int gc_ = g_ < 0 ? 0 : (g_ > HW-1 ? HW-1 : g_); \
  const float* xp_ = xb + gc_; \
  _Pragma("unroll") \
  for (int kc_=0;kc_<4;++kc_) \
    _Pragma("unroll") \
    for (int j_=0;j_<8;++j_) \
      dst[kc_*8+j_] = xp_[(size_t)(kc_*32 + kg*8 + j_)*HW]; }

// quantize + squeeze-MFMA + LDS write for local halo block bl from src[32]
#define PROCX(src, bl) { \
  const bf16x8* wsqf_ = (const bf16x8*)((const char*)ws + WSQF_BYTES_OFF); \
  bf16x8 W_[8]; \
  _Pragma("unroll") \
  for (int q_=0;q_<8;++q_) W_[q_] = wsqf_[q_*64 + lane]; \
  bf16x8 Bf_[4]; \
  _Pragma("unroll") \
  for (int kc_=0;kc_<4;++kc_){ \
    float m_[8]; \
    _Pragma("unroll") \
    for (int j_=0;j_<8;++j_){ \
      float v_ = fminf(fmaxf(src[kc_*8+j_],-4.f),4.f); \
      m_[j_] = fminf(rintf(v_*32.f), 127.f); \
    } \
    union { uint u[4]; bf16x8 v; } cv_; \
    _Pragma("unroll") \
    for (int q_=0;q_<4;++q_) cv_.u[q_] = pack2f(m_[q_*2], m_[q_*2+1]); \
    Bf_[kc_] = cv_.v; \
  } \
  f32x4 a0_ = (f32x4){0.f,0.f,0.f,0.f}; \
  f32x4 a1_ = (f32x4){0.f,0.f,0.f,0.f}; \
  _Pragma("unroll") \
  for (int kc_=0;kc_<4;++kc_){ \
    a0_ = __builtin_amdgcn_mfma_f32_16x16x32_bf16(W_[kc_],   Bf_[kc_], a0_, 0,0,0); \
    a1_ = __builtin_amdgcn_mfma_f32_16x16x32_bf16(W_[4+kc_], Bf_[kc_], a1_, 0,0,0); \
  } \
  int lp_ = (bl)*16 + colg; \
  int g_  = gbase + lp_; \
  int lr_ = lp_/WID, c_ = lp_ - lr_*WID; \
  int ph_ = lr_*58 + c_ + 1; \
  bool valid_ = (g_ >= 0) && (g_ < HW); \
  _Pragma("unroll") \
  for (int mf_=0;mf_<2;++mf_){ \
    f32x4 a_ = mf_ ? a1_ : a0_; \
    float m_[4]; \
    _Pragma("unroll") \
    for (int r_=0;r_<4;++r_){ \
      float y_ = fmaf(a_[r_], 0.000244140625f, bias[mf_][r_]); \
      y_ = fminf(fmaxf(y_,-8.f),8.f); \
      y_ = fminf(rintf(y_*16.f)*0.0625f, 7.9375f); \
      y_ = fmaxf(y_,0.f); \
      y_ = fminf(y_,4.f); \
      y_ = fminf(y_,0.9998779296875f); \
      m_[r_] = valid_ ? rintf(y_*32.f) : 0.f; \
    } \
    int chunk_ = mf_*2 + (kg>>1); \
    int idx_ = ph_*4 + (chunk_ ^ ((ph_>>1)&3)); \
    uint* dst_ = (uint*)&lds4[idx_] + (kg&1)*2; \
    dst_[0] = pack2f(m_[0], m_[1]); \
    dst_[1] = pack2f(m_[2], m_[3]); \
  } }

// Pipelined fused fire: 8-row tile, full 10-row LDS halo (monotone writes, no aliasing).
// Grid (7,32), 512 threads (8 waves). Wave w owns e1-group w and e3-group w.
// Iter i: load blocks for i+1 -> e1(center tap)+store -> e3(9 taps)+store -> squeeze -> barrier.
__global__ __launch_bounds__(512) void fire_kernel(const float* __restrict__ x,
    const float* __restrict__ ws, float* __restrict__ out){
  __shared__ uint4 lds4[2320];   // [10 rows][58 cols] x 32ci bf16 (64B), 16B-chunk XOR swizzle
  int bry = blockIdx.x;          // 0..6
  int n   = blockIdx.y;          // 0..31
  int tid = threadIdx.x, w = tid>>6, lane = tid&63;
  int colg = lane&15, kg = lane>>4;
  int R0 = bry*8;
  int gbase = (R0-1)*WID;        // global px of local halo px 0 (may be -56)
  const float* xb = x + (size_t)n*CIN*HW;

  float bias[2][4];
  #pragma unroll
  for (int mf=0;mf<2;++mf)
    #pragma unroll
    for (int r=0;r<4;++r) bias[mf][r] = ws[OFF_BSQ + mf*16 + kg*4 + r];

  uint4 z = make_uint4(0,0,0,0);
  for (int i=tid; i<2320; i+=512) lds4[i] = z;
  __syncthreads();               // zero-init (halo cols 0,57) visible before squeeze writes

  float xv[32];
  // prologue: halo blocks 0..15 (rows 0..4) -> covers expand-0's rows 0..3
  LOADX(xv, w);      PROCX(xv, w);
  LOADX(xv, w+8);    PROCX(xv, w+8);
  __syncthreads();

  const bf16x8* we1f = (const bf16x8*)((const char*)ws + WE1F_BYTES_OFF);
  const bf16x8* we3f = (const bf16x8*)((const char*)ws + WE3F_BYTES_OFF);
  const bf16x8* lbase = (const bf16x8*)lds4;
  float be1v = ws[OFF_BE + w*16 + colg];
  float be3v = ws[OFF_BE + 128 + w*16 + colg];

  for (int i=0;i<4;++i){
    // issue next squeeze-block loads early (hidden under expand compute)
    bool doProc = (i<2) || (i==2 && w<3);
    int nb = (i<2) ? (16 + i*8 + w) : (32 + w);
    if (doProc) LOADX(xv, nb);

    int baseh[7];
    #pragma unroll
    for (int nf=0;nf<7;++nf){
      int p = i*112 + nf*16 + colg;
      int rr = p/WID, c = p - rr*WID;
      baseh[nf] = (rr+1)*58 + c + 1;
    }

    // ---- e1: center tap only, store immediately (starts write stream early) ----
    {
      bf16x8 A0 = we1f[w*64 + lane];
      f32x4 acc1[7];
      #pragma unroll
      for (int nf=0;nf<7;++nf){
        int ph = baseh[nf];
        int idx = ph*4 + (kg ^ ((ph>>1)&3));
        acc1[nf] = __builtin_amdgcn_mfma_f32_16x16x32_bf16(lbase[idx], A0,
                     (f32x4){0.f,0.f,0.f,0.f}, 0,0,0);
      }
      int co = w*16 + colg;
      float* op = out + (size_t)(n*256+co)*HW + R0*WID + i*112 + kg*4;
      #pragma unroll
      for (int nf=0;nf<7;++nf){
        f32x4 a = acc1[nf], yv;
        #pragma unroll
        for (int r=0;r<4;++r){
          float y = fmaf(a[r], 0.000244140625f, be1v);
          y = fminf(fmaxf(y,-8.f),8.f);
          y = fminf(rintf(y*16.f)*0.0625f, 7.9375f);
          yv[r] = fmaxf(y,0.f);
        }
        *(f32x4*)(op + nf*16) = yv;
      }
    }

    // ---- e3: 9 taps ----
    {
      f32x4 acc[7];
      #pragma unroll
      for (int nf=0;nf<7;++nf) acc[nf] = (f32x4){0.f,0.f,0.f,0.f};
      #pragma unroll
      for (int t=0;t<9;++t){
        int off = (t/3 - 1)*58 + (t%3 - 1);
        bf16x8 A = we3f[(w*9+t)*64 + lane];
        #pragma unroll
        for (int nf=0;nf<7;++nf){
          int ph = baseh[nf] + off;
          int idx = ph*4 + (kg ^ ((ph>>1)&3));
          acc[nf] = __builtin_amdgcn_mfma_f32_16x16x32_bf16(lbase[idx], A, acc[nf], 0,0,0);
        }
      }
      int co = w*16 + colg;
      float* op = out + (size_t)(n*256+128+co)*HW + R0*WID + i*112 + kg*4;
      #pragma unroll
      for (int nf=0;nf<7;++nf){
        f32x4 a = acc[nf], yv;
        #pragma unroll
        for (int r=0;r<4;++r){
          float y = fmaf(a[r], 0.000244140625f, be3v);
          y = fminf(fmaxf(y,-8.f),8.f);
          y = fminf(rintf(y*16.f)*0.0625f, 7.9375f);
          yv[r] = fmaxf(y,0.f);
        }
        *(f32x4*)(op + nf*16) = yv;
      }
    }

    // ---- squeeze next blocks (rows strictly ahead of any read this iteration) ----
    if (doProc) PROCX(xv, nb);
    if (i<3) __syncthreads();
  }
}

extern "C" void kernel_launch(void* const* d_in, const int* in_sizes, int n_in,
                              void* d_out, int out_size, void* d_ws, size_t ws_size,
                              hipStream_t stream){
  const float* x   = (const float*)d_in[0];
  const float* wsq = (const float*)d_in[1];
  const float* bsq = (const float*)d_in[2];
  const float* we1 = (const float*)d_in[3];
  const float* be1 = (const float*)d_in[4];
  const float* we3 = (const float*)d_in[5];
  const float* be3 = (const float*)d_in[6];
  float* out = (float*)d_out;
  float* ws  = (float*)d_ws;

  hipLaunchKernelGGL(prep_kernel, dim3(64), dim3(256), 0, stream,
                     wsq, bsq, we1, be1, we3, be3, ws);
  hipLaunchKernelGGL(fire_kernel, dim3(7, 32), dim3(512), 0, stream, x, ws, out);
}

// Round 13
// 44.595 us; speedup vs baseline: 1.0877x; 1.0877x over previous
//
#include <hip/hip_runtime.h>
#include <stdint.h>

typedef __bf16 bf16x8 __attribute__((ext_vector_type(8)));
typedef float  f32x4  __attribute__((ext_vector_type(4)));

#define HW   3136
#define WID  56
#define CIN  128
#define SQ   32

// workspace layout (bytes unless noted)
#define OFF_BSQ 0              // f32[32]  (float offset 0)
#define OFF_BE  32             // f32[256] (float offset 32) e1 then e3
#define WSQF_BYTES_OFF 1152    // bf16 [2mf*4kc][64 lane][8] = 8192 B
#define WE1F_BYTES_OFF 9344    // bf16 [8 mf][64 lane][8] = 8192 B
#define WE3F_BYTES_OFF 17536   // bf16 [8 mf][9 tap][64 lane][8] = 73728 B

__device__ __forceinline__ float quant_w8(float x){
  float xc = fminf(fmaxf(x,-1.f),1.f);
  return fminf(rintf(xc*128.f)*0.0078125f, 0.9921875f);
}
// weight as integer n = 128*wq in [-128,127], stored as exact bf16
__device__ __forceinline__ ushort wq_int_bf16(float x){
  float xc = fminf(fmaxf(x,-1.f),1.f);
  float n = fminf(rintf(xc*128.f), 127.f);
  return (ushort)(__float_as_uint(n)>>16);
}
__device__ __forceinline__ uint pack2f(float a, float b){
  return (__float_as_uint(a)>>16) | (__float_as_uint(b)&0xffff0000u);
}
// verified expand epilogue: y = a/4096 + bias; q8@8; relu
__device__ __forceinline__ float eplg(float a, float bias){
  float y = fmaf(a, 0.000244140625f, bias);
  y = fminf(fmaxf(y,-8.f),8.f);
  y = fminf(rintf(y*16.f)*0.0625f, 7.9375f);
  return fmaxf(y,0.f);
}

__global__ void prep_kernel(const float* __restrict__ wsq, const float* __restrict__ bsq,
                            const float* __restrict__ we1, const float* __restrict__ be1,
                            const float* __restrict__ we3, const float* __restrict__ be3,
                            float* __restrict__ ws){
  int tid = blockIdx.x*blockDim.x+threadIdx.x;
  int nth = gridDim.x*blockDim.x;
  ushort* wsqf = (ushort*)((char*)ws + WSQF_BYTES_OFF);
  ushort* we1f = (ushort*)((char*)ws + WE1F_BYTES_OFF);
  ushort* we3f = (ushort*)((char*)ws + WE3F_BYTES_OFF);
  for (int i=tid;i<SQ;i+=nth) ws[OFF_BSQ+i]=quant_w8(bsq[i]);
  for (int i=tid;i<256;i+=nth) ws[OFF_BE+i] = (i<128)? quant_w8(be1[i]) : quant_w8(be3[i-128]);
  // squeeze W frags: A[co=mf*16+(l&15)][ci=kc*32+(l>>4)*8+j], src wsq (32,128)
  for (int i=tid;i<4096;i+=nth){
    int mfkc=i>>9, l=(i>>3)&63, j=i&7;
    int mf=mfkc>>2, kc=mfkc&3;
    int co=mf*16+(l&15), ci=kc*32+(l>>4)*8+j;
    wsqf[i] = wq_int_bf16(wsq[co*CIN+ci]);
  }
  // e1 frags: [co=mf*16+(l&15)][k=ci=(l>>4)*8+j], src we1 (128,32)
  for (int i=tid;i<4096;i+=nth){
    int mf=i>>9, l=(i>>3)&63, j=i&7;
    int co=mf*16+(l&15), ci=(l>>4)*8+j;
    we1f[i] = wq_int_bf16(we1[co*SQ+ci]);
  }
  // e3 frags per tap, src we3 (128,32,3,3)
  for (int i=tid;i<36864;i+=nth){
    int mf=i/4608, r=i-mf*4608, t=r>>9, l=(r>>3)&63, j=r&7;
    int co=mf*16+(l&15), ci=(l>>4)*8+j;
    we3f[i] = wq_int_bf16(we3[(co*SQ+ci)*9+t]);
  }
}

// Fused fire: squeeze (MFMA) -> LDS halo -> expand e1+e3 (MFMA) -> LDS-staged
// contiguous stores. 7-row tiles, grid 256 flat (XCD-grouped decode), 512 thr.
__global__ __launch_bounds__(512) void fire_kernel(const float* __restrict__ x,
    const float* __restrict__ ws, float* __restrict__ out){
  __shared__ uint4 lds4[2320];     // h halo [10 rows][58 cols] x 32ci bf16, XOR-swizzled
  __shared__ float stage[128*115]; // store transpose buffer [cout 128][px 112 pad 115]
  int wg = blockIdx.x;
  int logical = (wg & 7)*32 + (wg >> 3);
  int n   = logical >> 3;        // 0..31
  int bry = logical & 7;         // 0..7
  int tid = threadIdx.x, w = tid>>6, lane = tid&63;
  int colg = lane&15, kg = lane>>4;
  int R0 = bry*7;
  int vr0 = (R0==0) ? 0 : R0-1;
  int vr1 = (R0+7 > 55) ? 55 : R0+7;
  int limit = (vr1+1)*WID;
  int nblk = ((vr1-vr0+1)*WID + 15)>>4;
  int base_px = vr0*WID;

  uint4 z = make_uint4(0,0,0,0);
  for (int i=tid; i<2320; i+=512) lds4[i] = z;
  __syncthreads();

  // ---- phase 1: squeeze into LDS halo (verified integer-exact MFMA path) ----
  {
    const bf16x8* wsqf = (const bf16x8*)((const char*)ws + WSQF_BYTES_OFF);
    bf16x8 W[8];
    #pragma unroll
    for (int q=0;q<8;++q) W[q] = wsqf[q*64 + lane];
    float sbias[2][4];
    #pragma unroll
    for (int mf=0;mf<2;++mf)
      #pragma unroll
      for (int r=0;r<4;++r) sbias[mf][r] = ws[OFF_BSQ + mf*16 + kg*4 + r];

    for (int b=w; b<nblk; b+=8){
      int px = base_px + b*16 + colg;
      int pxc = (px < limit) ? px : (limit-1);
      const float* xp = x + (size_t)n*CIN*HW + pxc;
      float xv[32];
      #pragma unroll
      for (int kc=0;kc<4;++kc)
        #pragma unroll
        for (int j=0;j<8;++j)
          xv[kc*8+j] = xp[(size_t)(kc*32 + kg*8 + j)*HW];

      bf16x8 Bf[4];
      #pragma unroll
      for (int kc=0;kc<4;++kc){
        float m[8];
        #pragma unroll
        for (int j=0;j<8;++j){
          float v = fminf(fmaxf(xv[kc*8+j],-4.f),4.f);
          m[j] = fminf(rintf(v*32.f), 127.f);      // m = 32*xq, exact bf16
        }
        union { uint u[4]; bf16x8 v; } cv;
        #pragma unroll
        for (int q=0;q<4;++q) cv.u[q] = pack2f(m[q*2], m[q*2+1]);
        Bf[kc] = cv.v;
      }

      f32x4 acc0 = (f32x4){0.f,0.f,0.f,0.f};
      f32x4 acc1 = (f32x4){0.f,0.f,0.f,0.f};
      #pragma unroll
      for (int kc=0;kc<4;++kc){
        acc0 = __builtin_amdgcn_mfma_f32_16x16x32_bf16(W[kc],   Bf[kc], acc0, 0,0,0);
        acc1 = __builtin_amdgcn_mfma_f32_16x16x32_bf16(W[4+kc], Bf[kc], acc1, 0,0,0);
      }

      if (px < limit){
        int rr = px/WID, c = px - rr*WID;
        int ph = (rr - R0 + 1)*58 + c + 1;
        #pragma unroll
        for (int mf=0;mf<2;++mf){
          f32x4 a = mf ? acc1 : acc0;
          float m[4];
          #pragma unroll
          for (int r=0;r<4;++r){
            float y = fmaf(a[r], 0.000244140625f, sbias[mf][r]);
            y = fminf(fmaxf(y,-8.f),8.f);
            y = fminf(rintf(y*16.f)*0.0625f, 7.9375f);
            y = fmaxf(y,0.f);
            y = fminf(y,4.f);
            y = fminf(y,0.9998779296875f);
            m[r] = rintf(y*32.f);                // m32 in {0,2,...,32}, exact bf16
          }
          int chunk = mf*2 + (kg>>1);
          int idx = ph*4 + (chunk ^ ((ph>>1)&3));
          uint* dst = (uint*)&lds4[idx] + (kg&1)*2;
          dst[0] = pack2f(m[0], m[1]);
          dst[1] = pack2f(m[2], m[3]);
        }
      }
    }
  }
  __syncthreads();

  // ---- phase 2: expand with LDS-staged contiguous stores ----
  const bf16x8* we1f = (const bf16x8*)((const char*)ws + WE1F_BYTES_OFF);
  const bf16x8* we3f = (const bf16x8*)((const char*)ws + WE3F_BYTES_OFF);
  const bf16x8* lbase = (const bf16x8*)lds4;
  int lsub = lane & 31, lpl = lane >> 5;       // coop-store: 2 planes/instr

  for (int rp=0;rp<4;++rp){
    int npx = (rp==3) ? 56 : 112;              // tail row-pair is half
    bool act = (lsub < 28) && (lsub*4 < npx);
    size_t obase = (size_t)(n*256)*HW + R0*WID + rp*112 + lsub*4;

    int baseh[7];
    #pragma unroll
    for (int nf=0;nf<7;++nf){
      int p = rp*112 + nf*16 + colg;
      int rr = p/WID, c = p - rr*WID;
      baseh[nf] = (rr+1)*58 + c + 1;
    }

    // e1 compute (center tap, K=32, from-zero acc)
    f32x4 acc1[7];
    {
      bf16x8 A0 = we1f[w*64 + lane];
      #pragma unroll
      for (int nf=0;nf<7;++nf){
        int ph = baseh[nf];
        int idx = ph*4 + (kg ^ ((ph>>1)&3));
        acc1[nf] = __builtin_amdgcn_mfma_f32_16x16x32_bf16(lbase[idx], A0,
                     (f32x4){0.f,0.f,0.f,0.f}, 0,0,0);
      }
    }
    __syncthreads();                           // prev rp's stage reads done
    #pragma unroll
    for (int nf=0;nf<7;++nf)
      *(f32x4*)&stage[(w*16+colg)*115 + nf*16 + kg*4] = acc1[nf];
    __syncthreads();                           // stage filled
    // coop store e1: wave w -> planes w*16..+15, 2 planes / instruction
    #pragma unroll
    for (int q=0;q<8;++q){
      int p = w*16 + q*2 + lpl;
      float bias = ws[OFF_BE + p];
      f32x4 a = *(const f32x4*)&stage[p*115 + lsub*4];
      f32x4 yv;
      #pragma unroll
      for (int r=0;r<4;++r) yv[r] = eplg(a[r], bias);
      if (act) *(f32x4*)(out + obase + (size_t)p*HW) = yv;
    }

    // e3 compute (9 taps) — overlaps e1 store drain
    f32x4 acc3[7];
    #pragma unroll
    for (int nf=0;nf<7;++nf) acc3[nf] = (f32x4){0.f,0.f,0.f,0.f};
    #pragma unroll
    for (int t=0;t<9;++t){
      int off = (t/3 - 1)*58 + (t%3 - 1);
      bf16x8 A = we3f[(w*9+t)*64 + lane];
      #pragma unroll
      for (int nf=0;nf<7;++nf){
        int ph = baseh[nf] + off;
        int idx = ph*4 + (kg ^ ((ph>>1)&3));
        acc3[nf] = __builtin_amdgcn_mfma_f32_16x16x32_bf16(lbase[idx], A, acc3[nf], 0,0,0);
      }
    }
    __syncthreads();                           // e1 stage reads done
    #pragma unroll
    for (int nf=0;nf<7;++nf)
      *(f32x4*)&stage[(w*16+colg)*115 + nf*16 + kg*4] = acc3[nf];
    __syncthreads();                           // stage filled
    // coop store e3
    #pragma unroll
    for (int q=0;q<8;++q){
      int p = w*16 + q*2 + lpl;
      float bias = ws[OFF_BE + 128 + p];
      f32x4 a = *(const f32x4*)&stage[p*115 + lsub*4];
      f32x4 yv;
      #pragma unroll
      for (int r=0;r<4;++r) yv[r] = eplg(a[r], bias);
      if (act) *(f32x4*)(out + obase + (size_t)(128+p)*HW) = yv;
    }
  }
}

extern "C" void kernel_launch(void* const* d_in, const int* in_sizes, int n_in,
                              void* d_out, int out_size, void* d_ws, size_t ws_size,
                              hipStream_t stream){
  const float* x   = (const float*)d_in[0];
  const float* wsq = (const float*)d_in[1];
  const float* bsq = (const float*)d_in[2];
  const float* we1 = (const float*)d_in[3];
  const float* be1 = (const float*)d_in[4];
  const float* we3 = (const float*)d_in[5];
  const float* be3 = (const float*)d_in[6];
  float* out = (float*)d_out;
  float* ws  = (float*)d_ws;

  hipLaunchKernelGGL(prep_kernel, dim3(64), dim3(256), 0, stream,
                     wsq, bsq, we1, be1, we3, be3, ws);
  hipLaunchKernelGGL(fire_kernel, dim3(256), dim3(512), 0, stream, x, ws, out);
}